// Round 10
// baseline (204.074 us; speedup 1.0000x reference)
//
#include <hip/hip_runtime.h>
#include <cmath>

// ---------------------------------------------------------------------------
// GAT layer: N=100000 nodes, IN=128, OUT=32, H=4 (H*OUT=128), E=1.6M edges.
// Pipeline:
//   K1  k_gemm   : xw = x@W [N,128] packed bf16 (one 128x128 tile per block),
//                  fused a_src/a_dst logits [N,4] pre-scaled by log2(e)
//   CSR build (two-level bucketed, LDS-atomic only):
//     p1_hist    : per-block LDS histogram over NB dst-buckets (+btot atomics)
//     p2b_bscan  : exclusive scan of bucket totals -> bucket bases
//     p2c_brow   : per-bucket scan across blocks -> absolute block cursors
//     p3_part    : scatter packed (dloc<<24|src) into bucket segments
//     p4_local   : per-bucket: degree hist + scan -> offs; scatter srcs AND
//                  per-edge softmax numerators palpha16[e] (4 x f16, exp2 form)
//   K3  k_agg    : wave per node, 4 edges in flight per half-wave (8/wave),
//                  4 ch/lane via 8B bf16x4 gather; sum p, p*x; ELU; row write
// ---------------------------------------------------------------------------

#define LOG2E 1.44269504088896340736f

typedef float f32x2 __attribute__((ext_vector_type(2)));
typedef float f32x4 __attribute__((ext_vector_type(4)));
typedef unsigned u32x2 __attribute__((ext_vector_type(2)));

__device__ __forceinline__ float fast_exp2(float x) {
#if __has_builtin(__builtin_amdgcn_exp2f)
  return __builtin_amdgcn_exp2f(x);
#else
  return exp2f(x);
#endif
}

__device__ __forceinline__ unsigned bf16_rne(float f) {
  unsigned u = __float_as_uint(f);
  return (u + 0x7fffu + ((u >> 16) & 1u)) >> 16;
}
__device__ __forceinline__ float bf_lo(unsigned v) {
  return __uint_as_float(v << 16);
}
__device__ __forceinline__ float bf_hi(unsigned v) {
  return __uint_as_float(v & 0xffff0000u);
}
__device__ __forceinline__ float f16_at(unsigned w, int sh) {
  return (float)__builtin_bit_cast(_Float16, (unsigned short)(w >> sh));
}
// pack two f32 -> one u32 of 2 x f16 (RTZ)
__device__ __forceinline__ unsigned pk_f16(float a, float b) {
  auto h = __builtin_amdgcn_cvt_pkrtz(a, b);  // __fp16 ext_vector_type(2)
  return __builtin_bit_cast(unsigned, h);
}

// inclusive block scan; lds must hold >= blockDim/64 ints
__device__ __forceinline__ int blockInclScan(int v, int tid, int* lds) {
  int lane = tid & 63;
  int wid = tid >> 6;
#pragma unroll
  for (int off = 1; off < 64; off <<= 1) {
    int t = __shfl_up(v, off);
    if (lane >= off) v += t;
  }
  if (lane == 63) lds[wid] = v;
  __syncthreads();
  int add = 0;
  for (int i = 0; i < wid; ++i) add += lds[i];
  v += add;
  __syncthreads();
  return v;
}

// ---------------- K1: GEMM + attention logits ----------------
// grid ceil(N/128), block 256.  tx = tid&15 (16 col-groups of 8 = 128 cols),
// ty = tid>>4 (16 row-groups of 8 = 128 rows).  k-chunked by 32.
__global__ __launch_bounds__(256) void k_gemm(
    const float* __restrict__ x, const float* __restrict__ Wm,
    const float* __restrict__ att_src, const float* __restrict__ att_dst,
    unsigned* __restrict__ xwb, float* __restrict__ a_src,
    float* __restrict__ a_dst, int N) {
  __shared__ float xs_t[32][132];  // k-major x tile
  __shared__ float Wl[32][128];
  const int tid = threadIdx.x;
  const int tx = tid & 15;
  const int ty = tid >> 4;
  const int row0 = blockIdx.x * 128;

  float acc[8][8];
#pragma unroll
  for (int r = 0; r < 8; ++r)
#pragma unroll
    for (int c = 0; c < 8; ++c) acc[r][c] = 0.f;

  for (int kc = 0; kc < 4; ++kc) {
    __syncthreads();
    // stage x chunk: 128 rows x 32 k = 1024 float4, 4 per thread
#pragma unroll
    for (int j = 0; j < 4; ++j) {
      int f = tid + j * 256;
      int r = f >> 3, k4 = f & 7;
      int row = row0 + r;
      float4 v = make_float4(0.f, 0.f, 0.f, 0.f);
      if (row < N) v = *(const float4*)&x[(size_t)row * 128 + kc * 32 + k4 * 4];
      xs_t[k4 * 4 + 0][r] = v.x;
      xs_t[k4 * 4 + 1][r] = v.y;
      xs_t[k4 * 4 + 2][r] = v.z;
      xs_t[k4 * 4 + 3][r] = v.w;
    }
    // stage W chunk: 32 k x 128 cols = 1024 float4, 4 per thread
#pragma unroll
    for (int j = 0; j < 4; ++j) {
      int f = tid + j * 256;
      int kr = f >> 5, c4 = f & 31;
      *(float4*)&Wl[kr][c4 * 4] =
          *(const float4*)&Wm[(size_t)(kc * 32 + kr) * 128 + c4 * 4];
    }
    __syncthreads();
#pragma unroll 4
    for (int k = 0; k < 32; ++k) {
      float wv[8], xv[8];
      *(float4*)&wv[0] = *(const float4*)&Wl[k][tx * 8];
      *(float4*)&wv[4] = *(const float4*)&Wl[k][tx * 8 + 4];
      *(float4*)&xv[0] = *(const float4*)&xs_t[k][ty * 8];
      *(float4*)&xv[4] = *(const float4*)&xs_t[k][ty * 8 + 4];
#pragma unroll
      for (int r = 0; r < 8; ++r)
#pragma unroll
        for (int c = 0; c < 8; ++c) acc[r][c] = fmaf(xv[r], wv[c], acc[r][c]);
    }
  }

  float att_s[8], att_d[8];
#pragma unroll
  for (int c = 0; c < 8; ++c) {
    att_s[c] = att_src[tx * 8 + c];
    att_d[c] = att_dst[tx * 8 + c];
  }

#pragma unroll
  for (int r = 0; r < 8; ++r) {
    int row = row0 + ty * 8 + r;
    bool ok = row < N;
    float vs = 0.f, vd = 0.f;
#pragma unroll
    for (int c = 0; c < 8; ++c) {
      vs += acc[r][c] * att_s[c];
      vd += acc[r][c] * att_d[c];
    }
    // reduce across the 4 tx-lanes (32 cols) of each head
    vs += __shfl_xor(vs, 1);
    vs += __shfl_xor(vs, 2);
    vd += __shfl_xor(vd, 1);
    vd += __shfl_xor(vd, 2);
    if (ok) {
      uint4 pk;
      pk.x = bf16_rne(acc[r][0]) | (bf16_rne(acc[r][1]) << 16);
      pk.y = bf16_rne(acc[r][2]) | (bf16_rne(acc[r][3]) << 16);
      pk.z = bf16_rne(acc[r][4]) | (bf16_rne(acc[r][5]) << 16);
      pk.w = bf16_rne(acc[r][6]) | (bf16_rne(acc[r][7]) << 16);
      *(uint4*)&xwb[(size_t)row * 64 + tx * 4] = pk;
      if ((tx & 3) == 0) {
        a_src[row * 4 + (tx >> 2)] = vs * LOG2E;
        a_dst[row * 4 + (tx >> 2)] = vd * LOG2E;
      }
    }
  }
}

// ---------------- bucketed CSR build ----------------
#define CHUNK 4096

// P1: per-block histogram over buckets -> bh[b*NBLK + blk]; btot via atomics
__global__ __launch_bounds__(256) void p1_hist(const int* __restrict__ ei, int E,
                                               int EL, int NB, int NBLK,
                                               int* __restrict__ bh,
                                               int* __restrict__ btot) {
  __shared__ int lh[512];
  int tid = threadIdx.x;
  lh[tid] = 0;
  lh[tid + 256] = 0;
  __syncthreads();
  int base_e = blockIdx.x * CHUNK;
#pragma unroll
  for (int j = 0; j < CHUNK / 256; ++j) {
    int e = base_e + j * 256 + tid;
    if (e < EL) {
      int dst = (e < E) ? ei[E + e] : (e - E);
      atomicAdd(&lh[dst >> 8], 1);
    }
  }
  __syncthreads();
  for (int b = tid; b < NB; b += 256) {
    int c = lh[b];
    bh[(size_t)b * NBLK + blockIdx.x] = c;
    if (c) atomicAdd(&btot[b], c);
  }
}

// P2b: exclusive scan of bucket totals -> bbase  (single block, 512 threads)
__global__ __launch_bounds__(512) void p2b_bscan(const int* __restrict__ btot,
                                                 int* __restrict__ bbase, int NB) {
  __shared__ int lds[8];
  int i = threadIdx.x;
  int v = (i < NB) ? btot[i] : 0;
  int incl = blockInclScan(v, i, lds);
  if (i < NB) bbase[i] = incl - v;
}

// P2c: per-bucket exclusive scan across blocks (row of bh), + bbase (NBLK<=512)
__global__ __launch_bounds__(256) void p2c_brow(int* __restrict__ bh,
                                                const int* __restrict__ bbase,
                                                int NBLK) {
  __shared__ int lds[4];
  __shared__ int ctot;
  int b = blockIdx.x;
  int tid = threadIdx.x;
  int base = bbase[b];
  int v0 = (tid < NBLK) ? bh[(size_t)b * NBLK + tid] : 0;
  int incl0 = blockInclScan(v0, tid, lds);
  if (tid < NBLK) bh[(size_t)b * NBLK + tid] = base + incl0 - v0;
  if (tid == 255) ctot = incl0;
  __syncthreads();
  int base1 = base + ctot;
  int j = 256 + tid;
  int v1 = (j < NBLK) ? bh[(size_t)b * NBLK + j] : 0;
  int incl1 = blockInclScan(v1, tid, lds);
  if (j < NBLK) bh[(size_t)b * NBLK + j] = base1 + incl1 - v1;
}

// P3: partition edges into bucket segments, packed word (dloc<<24 | src)
__global__ __launch_bounds__(256) void p3_part(const int* __restrict__ ei, int E,
                                               int EL, int NB, int NBLK,
                                               const int* __restrict__ bh,
                                               unsigned* __restrict__ tmp) {
  __shared__ int lc[512];
  int tid = threadIdx.x;
  for (int b = tid; b < NB; b += 256) lc[b] = bh[(size_t)b * NBLK + blockIdx.x];
  __syncthreads();
  int base_e = blockIdx.x * CHUNK;
#pragma unroll
  for (int j = 0; j < CHUNK / 256; ++j) {
    int e = base_e + j * 256 + tid;
    if (e < EL) {
      int src, dst;
      if (e < E) {
        src = ei[e];
        dst = ei[E + e];
      } else {
        src = e - E;
        dst = e - E;
      }
      int pos = atomicAdd(&lc[dst >> 8], 1);
      tmp[pos] = ((unsigned)(dst & 255) << 24) | (unsigned)src;
    }
  }
}

// P4: per-bucket local CSR (512 threads): LDS degree hist + scan -> offs;
// scatter srcs AND per-edge softmax numerators palpha16[pos] = 4 x f16
// (exp2 form; logits already scaled by log2e).
__global__ __launch_bounds__(512) void p4_local(const unsigned* __restrict__ tmp,
                                                const int* __restrict__ bbase,
                                                const int* __restrict__ btot,
                                                const float* __restrict__ asrc,
                                                const float* __restrict__ adst,
                                                int N, int NB, int EL,
                                                int* __restrict__ offs,
                                                int* __restrict__ srcs,
                                                unsigned* __restrict__ palpha16) {
  __shared__ int deg[256];
  __shared__ int cur[256];
  __shared__ f32x4 ads[256];
  __shared__ int lds[8];
  int b = blockIdx.x;
  int tid = threadIdx.x;
  int beg = bbase[b];
  int end = beg + btot[b];
  if (tid < 256) {
    deg[tid] = 0;
    int idx = b * 256 + tid;
    f32x4 z = {0.f, 0.f, 0.f, 0.f};
    ads[tid] = (idx < N) ? *(const f32x4*)&adst[idx * 4] : z;
  }
  __syncthreads();
  for (int k = beg + tid; k < end; k += 512) {
    unsigned w = tmp[k];
    atomicAdd(&deg[w >> 24], 1);
  }
  __syncthreads();
  int v = (tid < 256) ? deg[tid] : 0;
  int incl = blockInclScan(v, tid, lds);
  if (tid < 256) {
    int excl = incl - v;
    int idx = b * 256 + tid;
    if (idx < N) offs[idx] = beg + excl;
    cur[tid] = beg + excl;
  }
  if (b == NB - 1 && tid == 0) offs[N] = EL;
  __syncthreads();
  for (int k = beg + tid; k < end; k += 512) {
    unsigned w = tmp[k];
    int dloc = w >> 24;
    int src = (int)(w & 0xFFFFFFu);
    int pos = atomicAdd(&cur[dloc], 1);
    srcs[pos] = src;
    f32x4 as = *(const f32x4*)&asrc[src * 4];
    f32x4 ad = ads[dloc];
    float t0 = as.x + ad.x, t1 = as.y + ad.y, t2 = as.z + ad.z, t3 = as.w + ad.w;
    float p0 = fast_exp2(fmaxf(t0, 0.2f * t0));
    float p1 = fast_exp2(fmaxf(t1, 0.2f * t1));
    float p2 = fast_exp2(fmaxf(t2, 0.2f * t2));
    float p3 = fast_exp2(fmaxf(t3, 0.2f * t3));
    u32x2 st;
    st.x = pk_f16(p0, p1);
    st.y = pk_f16(p2, p3);
    *(u32x2*)&palpha16[(size_t)pos * 2] = st;
  }
}

// ---------------- K3: per-node aggregate ----------------
// wave per node; half-wave 0 = even edges, half-wave 1 = odd edges.
// lane covers 4 channels (uint2 = 4 bf16).  4 edges in flight per half-wave.
__global__ __launch_bounds__(256) void k_agg(
    const int* __restrict__ srcs, const int* __restrict__ offs,
    const unsigned* __restrict__ xwb, const unsigned* __restrict__ palpha16,
    const float* __restrict__ bias, float* __restrict__ out, int N) {
  int gw = (int)(((size_t)blockIdx.x * blockDim.x + threadIdx.x) >> 6);
  int lane = threadIdx.x & 63;
  if (gw >= N) return;
  int beg = offs[gw];
  int end = offs[gw + 1];
  int half = lane >> 5;
  int l5 = lane & 31;
  int h = l5 >> 3;           // head of this lane's 4 channels
  int hw = h >> 1;           // which palpha16 word
  int hsh = (h & 1) * 16;    // shift within word
  const unsigned* xr = xwb + l5 * 2;

  float sA = 0.f, sB = 0.f;
  float a0 = 0.f, a1 = 0.f, a2 = 0.f, a3 = 0.f;
  float b0 = 0.f, b1 = 0.f, b2 = 0.f, b3 = 0.f;
  int i = beg + half;
  // main: 4 edges per half-wave in flight (8 per wave)
  for (; i + 6 < end; i += 8) {
    int eA = srcs[i], eB = srcs[i + 2], eC = srcs[i + 4], eD = srcs[i + 6];
    unsigned wA = palpha16[(size_t)i * 2 + hw];
    unsigned wB = palpha16[(size_t)(i + 2) * 2 + hw];
    unsigned wC = palpha16[(size_t)(i + 4) * 2 + hw];
    unsigned wD = palpha16[(size_t)(i + 6) * 2 + hw];
    uint2 vA = *(const uint2*)(xr + (size_t)eA * 64);
    uint2 vB = *(const uint2*)(xr + (size_t)eB * 64);
    uint2 vC = *(const uint2*)(xr + (size_t)eC * 64);
    uint2 vD = *(const uint2*)(xr + (size_t)eD * 64);
    float pA = f16_at(wA, hsh);
    float pB = f16_at(wB, hsh);
    float pC = f16_at(wC, hsh);
    float pD = f16_at(wD, hsh);
    sA += pA + pC;
    sB += pB + pD;
    a0 = fmaf(pA, bf_lo(vA.x), a0);
    a1 = fmaf(pA, bf_hi(vA.x), a1);
    a2 = fmaf(pA, bf_lo(vA.y), a2);
    a3 = fmaf(pA, bf_hi(vA.y), a3);
    b0 = fmaf(pB, bf_lo(vB.x), b0);
    b1 = fmaf(pB, bf_hi(vB.x), b1);
    b2 = fmaf(pB, bf_lo(vB.y), b2);
    b3 = fmaf(pB, bf_hi(vB.y), b3);
    a0 = fmaf(pC, bf_lo(vC.x), a0);
    a1 = fmaf(pC, bf_hi(vC.x), a1);
    a2 = fmaf(pC, bf_lo(vC.y), a2);
    a3 = fmaf(pC, bf_hi(vC.y), a3);
    b0 = fmaf(pD, bf_lo(vD.x), b0);
    b1 = fmaf(pD, bf_hi(vD.x), b1);
    b2 = fmaf(pD, bf_lo(vD.y), b2);
    b3 = fmaf(pD, bf_hi(vD.y), b3);
  }
  // remainder: one edge at a time for this half
  for (; i < end; i += 2) {
    int eA = srcs[i];
    unsigned wA = palpha16[(size_t)i * 2 + hw];
    uint2 vA = *(const uint2*)(xr + (size_t)eA * 64);
    float pA = f16_at(wA, hsh);
    sA += pA;
    a0 = fmaf(pA, bf_lo(vA.x), a0);
    a1 = fmaf(pA, bf_hi(vA.x), a1);
    a2 = fmaf(pA, bf_lo(vA.y), a2);
    a3 = fmaf(pA, bf_hi(vA.y), a3);
  }
  float s = sA + sB;
  a0 += b0;
  a1 += b1;
  a2 += b2;
  a3 += b3;
  // combine the two halves (even/odd edge partial sums)
  s += __shfl_xor(s, 32);
  a0 += __shfl_xor(a0, 32);
  a1 += __shfl_xor(a1, 32);
  a2 += __shfl_xor(a2, 32);
  a3 += __shfl_xor(a3, 32);

  if (half == 0) {
    float inv = 1.f / s;
    float4 bv = *(const float4*)&bias[l5 * 4];
    float o0 = fmaf(a0, inv, bv.x);
    float o1 = fmaf(a1, inv, bv.y);
    float o2 = fmaf(a2, inv, bv.z);
    float o3 = fmaf(a3, inv, bv.w);
    o0 = o0 > 0.f ? o0 : fast_exp2(o0 * LOG2E) - 1.f;  // ELU
    o1 = o1 > 0.f ? o1 : fast_exp2(o1 * LOG2E) - 1.f;
    o2 = o2 > 0.f ? o2 : fast_exp2(o2 * LOG2E) - 1.f;
    o3 = o3 > 0.f ? o3 : fast_exp2(o3 * LOG2E) - 1.f;
    f32x4 o = {o0, o1, o2, o3};
    __builtin_nontemporal_store(o, (f32x4*)&out[(size_t)gw * 128 + l5 * 4]);
  }
}

// ---------------------------------------------------------------------------
extern "C" void kernel_launch(void* const* d_in, const int* in_sizes, int n_in,
                              void* d_out, int out_size, void* d_ws, size_t ws_size,
                              hipStream_t stream) {
  const float* x = (const float*)d_in[0];
  const int* ei = (const int*)d_in[1];
  const float* Wm = (const float*)d_in[2];
  const float* att_src = (const float*)d_in[3];
  const float* att_dst = (const float*)d_in[4];
  const float* bias = (const float*)d_in[5];
  float* out = (float*)d_out;

  const int N = in_sizes[0] / 128;
  const int E = in_sizes[1] / 2;
  const int EL = E + N;
  const int NB = (N + 255) >> 8;
  const int NBLK = (EL + CHUNK - 1) / CHUNK;

  size_t off = 0;
  auto carve = [&](size_t bytes) -> void* {
    void* p = (char*)d_ws + off;
    off += (bytes + 255) & ~(size_t)255;
    return p;
  };
  unsigned* xwb = (unsigned*)carve((size_t)N * 64 * 4);  // bf16-packed [N][64]
  float* a_src = (float*)carve((size_t)N * 4 * 4);
  float* a_dst = (float*)carve((size_t)N * 4 * 4);
  int* offs = (int*)carve((size_t)(N + 1) * 4);
  int* srcs = (int*)carve((size_t)EL * 4);
  unsigned* tmp = (unsigned*)carve((size_t)EL * 4);
  unsigned* palpha16 = (unsigned*)carve((size_t)EL * 8);  // 4 x f16 per edge
  int* bh = (int*)carve((size_t)NB * NBLK * 4);
  int* btot = (int*)carve((size_t)NB * 4);
  int* bbase = (int*)carve((size_t)NB * 4);

  (void)hipMemsetAsync(btot, 0, (size_t)NB * 4, stream);

  k_gemm<<<(N + 127) / 128, 256, 0, stream>>>(x, Wm, att_src, att_dst, xwb,
                                              a_src, a_dst, N);

  p1_hist<<<NBLK, 256, 0, stream>>>(ei, E, EL, NB, NBLK, bh, btot);
  p2b_bscan<<<1, 512, 0, stream>>>(btot, bbase, NB);
  p2c_brow<<<NB, 256, 0, stream>>>(bh, bbase, NBLK);
  p3_part<<<NBLK, 256, 0, stream>>>(ei, E, EL, NB, NBLK, bh, tmp);
  p4_local<<<NB, 512, 0, stream>>>(tmp, bbase, btot, a_src, a_dst, N, NB, EL,
                                   offs, srcs, palpha16);

  int abl = (int)(((size_t)N * 64 + 255) / 256);
  k_agg<<<abl, 256, 0, stream>>>(srcs, offs, xwb, palpha16, bias, out, N);
}

// Round 11
// 203.466 us; speedup vs baseline: 1.0030x; 1.0030x over previous
//
#include <hip/hip_runtime.h>
#include <cmath>

// ---------------------------------------------------------------------------
// GAT layer: N=100000 nodes, IN=128, OUT=32, H=4 (H*OUT=128), E=1.6M edges.
// Pipeline (6 dispatches):
//   A   k_fusedA : blocks [0,GB): xw = x@W bf16-packed + a_src/a_dst logits
//                  blocks [GB,GB+NBLK): p1 bucket histogram (independent)
//   p2c_brow     : per-bucket: base = sum(btot[<b]) (folded p2b) + scan across
//                  blocks -> absolute block cursors, writes bbase
//   p3_part      : scatter packed (dloc<<24|src) into bucket segments
//   p4_local     : per-bucket: degree hist + scan -> offs; scatter srcs AND
//                  per-edge softmax numerators palpha16[e] (4 x f16, exp2 form)
//   k_agg        : wave per node, 8 edges in flight per half-wave (16/wave),
//                  4 ch/lane via 8B bf16x4 gather; NT loads for edge streams
// ---------------------------------------------------------------------------

#define LOG2E 1.44269504088896340736f

typedef float f32x2 __attribute__((ext_vector_type(2)));
typedef float f32x4 __attribute__((ext_vector_type(4)));
typedef unsigned u32x2 __attribute__((ext_vector_type(2)));

__device__ __forceinline__ float fast_exp2(float x) {
#if __has_builtin(__builtin_amdgcn_exp2f)
  return __builtin_amdgcn_exp2f(x);
#else
  return exp2f(x);
#endif
}

__device__ __forceinline__ unsigned bf16_rne(float f) {
  unsigned u = __float_as_uint(f);
  return (u + 0x7fffu + ((u >> 16) & 1u)) >> 16;
}
__device__ __forceinline__ float bf_lo(unsigned v) {
  return __uint_as_float(v << 16);
}
__device__ __forceinline__ float bf_hi(unsigned v) {
  return __uint_as_float(v & 0xffff0000u);
}
__device__ __forceinline__ float f16_at(unsigned w, int sh) {
  return (float)__builtin_bit_cast(_Float16, (unsigned short)(w >> sh));
}
// pack two f32 -> one u32 of 2 x f16 (RTZ)
__device__ __forceinline__ unsigned pk_f16(float a, float b) {
  auto h = __builtin_amdgcn_cvt_pkrtz(a, b);  // __fp16 ext_vector_type(2)
  return __builtin_bit_cast(unsigned, h);
}

// inclusive block scan; lds must hold >= blockDim/64 ints
__device__ __forceinline__ int blockInclScan(int v, int tid, int* lds) {
  int lane = tid & 63;
  int wid = tid >> 6;
#pragma unroll
  for (int off = 1; off < 64; off <<= 1) {
    int t = __shfl_up(v, off);
    if (lane >= off) v += t;
  }
  if (lane == 63) lds[wid] = v;
  __syncthreads();
  int add = 0;
  for (int i = 0; i < wid; ++i) add += lds[i];
  v += add;
  __syncthreads();
  return v;
}

#define CHUNK 4096

// ---------------- A: fused GEMM + p1 histogram ----------------
// blocks [0,GB): GEMM 128x128 tile; blocks [GB,GB+NBLK): edge bucket histogram
__global__ __launch_bounds__(256) void k_fusedA(
    const float* __restrict__ x, const float* __restrict__ Wm,
    const float* __restrict__ att_src, const float* __restrict__ att_dst,
    unsigned* __restrict__ xwb, float* __restrict__ a_src,
    float* __restrict__ a_dst, int N, int GB,
    const int* __restrict__ ei, int E, int EL, int NB, int NBLK,
    int* __restrict__ bh, int* __restrict__ btot) {
  __shared__ __align__(16) char sm[33280];
  const int tid = threadIdx.x;

  if ((int)blockIdx.x >= GB) {
    // ---------------- p1 histogram body ----------------
    int blk = blockIdx.x - GB;
    int* lh = (int*)sm;
    lh[tid] = 0;
    lh[tid + 256] = 0;
    __syncthreads();
    int base_e = blk * CHUNK;
#pragma unroll
    for (int j = 0; j < CHUNK / 256; ++j) {
      int e = base_e + j * 256 + tid;
      if (e < EL) {
        int dst = (e < E) ? ei[E + e] : (e - E);
        atomicAdd(&lh[dst >> 8], 1);
      }
    }
    __syncthreads();
    for (int b = tid; b < NB; b += 256) {
      int c = lh[b];
      bh[(size_t)b * NBLK + blk] = c;
      if (c) atomicAdd(&btot[b], c);
    }
    return;
  }

  // ---------------- GEMM body ----------------
  float (*xs_t)[132] = (float(*)[132])sm;            // 32*132*4 = 16896 B
  float (*Wl)[128] = (float(*)[128])(sm + 16896);    // 32*128*4 = 16384 B
  const int tx = tid & 15;
  const int ty = tid >> 4;
  const int row0 = blockIdx.x * 128;

  float acc[8][8];
#pragma unroll
  for (int r = 0; r < 8; ++r)
#pragma unroll
    for (int c = 0; c < 8; ++c) acc[r][c] = 0.f;

  for (int kc = 0; kc < 4; ++kc) {
    __syncthreads();
#pragma unroll
    for (int j = 0; j < 4; ++j) {
      int f = tid + j * 256;
      int r = f >> 3, k4 = f & 7;
      int row = row0 + r;
      float4 v = make_float4(0.f, 0.f, 0.f, 0.f);
      if (row < N) v = *(const float4*)&x[(size_t)row * 128 + kc * 32 + k4 * 4];
      xs_t[k4 * 4 + 0][r] = v.x;
      xs_t[k4 * 4 + 1][r] = v.y;
      xs_t[k4 * 4 + 2][r] = v.z;
      xs_t[k4 * 4 + 3][r] = v.w;
    }
#pragma unroll
    for (int j = 0; j < 4; ++j) {
      int f = tid + j * 256;
      int kr = f >> 5, c4 = f & 31;
      *(float4*)&Wl[kr][c4 * 4] =
          *(const float4*)&Wm[(size_t)(kc * 32 + kr) * 128 + c4 * 4];
    }
    __syncthreads();
#pragma unroll 4
    for (int k = 0; k < 32; ++k) {
      float wv[8], xv[8];
      *(float4*)&wv[0] = *(const float4*)&Wl[k][tx * 8];
      *(float4*)&wv[4] = *(const float4*)&Wl[k][tx * 8 + 4];
      *(float4*)&xv[0] = *(const float4*)&xs_t[k][ty * 8];
      *(float4*)&xv[4] = *(const float4*)&xs_t[k][ty * 8 + 4];
#pragma unroll
      for (int r = 0; r < 8; ++r)
#pragma unroll
        for (int c = 0; c < 8; ++c) acc[r][c] = fmaf(xv[r], wv[c], acc[r][c]);
    }
  }

  float att_s[8], att_d[8];
#pragma unroll
  for (int c = 0; c < 8; ++c) {
    att_s[c] = att_src[tx * 8 + c];
    att_d[c] = att_dst[tx * 8 + c];
  }

#pragma unroll
  for (int r = 0; r < 8; ++r) {
    int row = row0 + ty * 8 + r;
    bool ok = row < N;
    float vs = 0.f, vd = 0.f;
#pragma unroll
    for (int c = 0; c < 8; ++c) {
      vs += acc[r][c] * att_s[c];
      vd += acc[r][c] * att_d[c];
    }
    vs += __shfl_xor(vs, 1);
    vs += __shfl_xor(vs, 2);
    vd += __shfl_xor(vd, 1);
    vd += __shfl_xor(vd, 2);
    if (ok) {
      uint4 pk;
      pk.x = bf16_rne(acc[r][0]) | (bf16_rne(acc[r][1]) << 16);
      pk.y = bf16_rne(acc[r][2]) | (bf16_rne(acc[r][3]) << 16);
      pk.z = bf16_rne(acc[r][4]) | (bf16_rne(acc[r][5]) << 16);
      pk.w = bf16_rne(acc[r][6]) | (bf16_rne(acc[r][7]) << 16);
      *(uint4*)&xwb[(size_t)row * 64 + tx * 4] = pk;
      if ((tx & 3) == 0) {
        a_src[row * 4 + (tx >> 2)] = vs * LOG2E;
        a_dst[row * 4 + (tx >> 2)] = vd * LOG2E;
      }
    }
  }
}

// ---------------- P2c: fused bucket-base + per-bucket row scan ----------------
__global__ __launch_bounds__(256) void p2c_brow(int* __restrict__ bh,
                                                const int* __restrict__ btot,
                                                int* __restrict__ bbase,
                                                int NB, int NBLK) {
  __shared__ int lds[4];
  __shared__ int ctot;
  __shared__ int red[256];
  int b = blockIdx.x;
  int tid = threadIdx.x;
  // base = sum of btot[j] for j < b (folded p2b)
  int part = 0;
  for (int j = tid; j < b; j += 256) part += btot[j];
  red[tid] = part;
  __syncthreads();
  for (int st = 128; st > 0; st >>= 1) {
    if (tid < st) red[tid] += red[tid + st];
    __syncthreads();
  }
  int base = red[0];
  if (tid == 0) bbase[b] = base;
  __syncthreads();
  int v0 = (tid < NBLK) ? bh[(size_t)b * NBLK + tid] : 0;
  int incl0 = blockInclScan(v0, tid, lds);
  if (tid < NBLK) bh[(size_t)b * NBLK + tid] = base + incl0 - v0;
  if (tid == 255) ctot = incl0;
  __syncthreads();
  int base1 = base + ctot;
  int j = 256 + tid;
  int v1 = (j < NBLK) ? bh[(size_t)b * NBLK + j] : 0;
  int incl1 = blockInclScan(v1, tid, lds);
  if (j < NBLK) bh[(size_t)b * NBLK + j] = base1 + incl1 - v1;
}

// P3: partition edges into bucket segments, packed word (dloc<<24 | src)
__global__ __launch_bounds__(256) void p3_part(const int* __restrict__ ei, int E,
                                               int EL, int NB, int NBLK,
                                               const int* __restrict__ bh,
                                               unsigned* __restrict__ tmp) {
  __shared__ int lc[512];
  int tid = threadIdx.x;
  for (int b = tid; b < NB; b += 256) lc[b] = bh[(size_t)b * NBLK + blockIdx.x];
  __syncthreads();
  int base_e = blockIdx.x * CHUNK;
#pragma unroll
  for (int j = 0; j < CHUNK / 256; ++j) {
    int e = base_e + j * 256 + tid;
    if (e < EL) {
      int src, dst;
      if (e < E) {
        src = ei[e];
        dst = ei[E + e];
      } else {
        src = e - E;
        dst = e - E;
      }
      int pos = atomicAdd(&lc[dst >> 8], 1);
      tmp[pos] = ((unsigned)(dst & 255) << 24) | (unsigned)src;
    }
  }
}

// P4: per-bucket local CSR (512 threads): LDS degree hist + scan -> offs;
// scatter srcs AND per-edge softmax numerators palpha16[pos] = 4 x f16
__global__ __launch_bounds__(512) void p4_local(const unsigned* __restrict__ tmp,
                                                const int* __restrict__ bbase,
                                                const int* __restrict__ btot,
                                                const float* __restrict__ asrc,
                                                const float* __restrict__ adst,
                                                int N, int NB, int EL,
                                                int* __restrict__ offs,
                                                int* __restrict__ srcs,
                                                unsigned* __restrict__ palpha16) {
  __shared__ int deg[256];
  __shared__ int cur[256];
  __shared__ f32x4 ads[256];
  __shared__ int lds[8];
  int b = blockIdx.x;
  int tid = threadIdx.x;
  int beg = bbase[b];
  int end = beg + btot[b];
  if (tid < 256) {
    deg[tid] = 0;
    int idx = b * 256 + tid;
    f32x4 z = {0.f, 0.f, 0.f, 0.f};
    ads[tid] = (idx < N) ? *(const f32x4*)&adst[idx * 4] : z;
  }
  __syncthreads();
  for (int k = beg + tid; k < end; k += 512) {
    unsigned w = tmp[k];
    atomicAdd(&deg[w >> 24], 1);
  }
  __syncthreads();
  int v = (tid < 256) ? deg[tid] : 0;
  int incl = blockInclScan(v, tid, lds);
  if (tid < 256) {
    int excl = incl - v;
    int idx = b * 256 + tid;
    if (idx < N) offs[idx] = beg + excl;
    cur[tid] = beg + excl;
  }
  if (b == NB - 1 && tid == 0) offs[N] = EL;
  __syncthreads();
  for (int k = beg + tid; k < end; k += 512) {
    unsigned w = tmp[k];
    int dloc = w >> 24;
    int src = (int)(w & 0xFFFFFFu);
    int pos = atomicAdd(&cur[dloc], 1);
    srcs[pos] = src;
    f32x4 as = *(const f32x4*)&asrc[src * 4];
    f32x4 ad = ads[dloc];
    float t0 = as.x + ad.x, t1 = as.y + ad.y, t2 = as.z + ad.z, t3 = as.w + ad.w;
    float p0 = fast_exp2(fmaxf(t0, 0.2f * t0));
    float p1 = fast_exp2(fmaxf(t1, 0.2f * t1));
    float p2 = fast_exp2(fmaxf(t2, 0.2f * t2));
    float p3 = fast_exp2(fmaxf(t3, 0.2f * t3));
    u32x2 st;
    st.x = pk_f16(p0, p1);
    st.y = pk_f16(p2, p3);
    *(u32x2*)&palpha16[(size_t)pos * 2] = st;
  }
}

// ---------------- K3: per-node aggregate ----------------
// wave per node; half-wave 0 = even edges, half-wave 1 = odd edges.
// lane covers 4 channels (uint2 = 4 bf16).  8 edges in flight per half-wave.
__global__ __launch_bounds__(256) void k_agg(
    const int* __restrict__ srcs, const int* __restrict__ offs,
    const unsigned* __restrict__ xwb, const unsigned* __restrict__ palpha16,
    const float* __restrict__ bias, float* __restrict__ out, int N) {
  int gw = (int)(((size_t)blockIdx.x * blockDim.x + threadIdx.x) >> 6);
  int lane = threadIdx.x & 63;
  if (gw >= N) return;
  int beg = offs[gw];
  int end = offs[gw + 1];
  int half = lane >> 5;
  int l5 = lane & 31;
  int h = l5 >> 3;           // head of this lane's 4 channels
  int hw = h >> 1;           // which palpha16 word
  int hsh = (h & 1) * 16;    // shift within word
  const unsigned* xr = xwb + l5 * 2;

  float sA = 0.f, sB = 0.f;
  float a0 = 0.f, a1 = 0.f, a2 = 0.f, a3 = 0.f;
  float b0 = 0.f, b1 = 0.f, b2 = 0.f, b3 = 0.f;
  int i = beg + half;
  // main: 8 edges per half-wave in flight (16 per wave)
  for (; i + 14 < end; i += 16) {
    int e[8];
    unsigned w[8];
    uint2 v[8];
    float p[8];
#pragma unroll
    for (int j = 0; j < 8; ++j)
      e[j] = __builtin_nontemporal_load(&srcs[i + 2 * j]);
#pragma unroll
    for (int j = 0; j < 8; ++j)
      w[j] = __builtin_nontemporal_load(&palpha16[(size_t)(i + 2 * j) * 2 + hw]);
#pragma unroll
    for (int j = 0; j < 8; ++j)
      v[j] = *(const uint2*)(xr + (size_t)e[j] * 64);
#pragma unroll
    for (int j = 0; j < 8; ++j) p[j] = f16_at(w[j], hsh);
#pragma unroll
    for (int j = 0; j < 8; j += 2) {
      sA += p[j];
      sB += p[j + 1];
      a0 = fmaf(p[j], bf_lo(v[j].x), a0);
      a1 = fmaf(p[j], bf_hi(v[j].x), a1);
      a2 = fmaf(p[j], bf_lo(v[j].y), a2);
      a3 = fmaf(p[j], bf_hi(v[j].y), a3);
      b0 = fmaf(p[j + 1], bf_lo(v[j + 1].x), b0);
      b1 = fmaf(p[j + 1], bf_hi(v[j + 1].x), b1);
      b2 = fmaf(p[j + 1], bf_lo(v[j + 1].y), b2);
      b3 = fmaf(p[j + 1], bf_hi(v[j + 1].y), b3);
    }
  }
  // secondary: 2 edges per half-wave
  for (; i + 2 < end; i += 4) {
    int eA = srcs[i], eB = srcs[i + 2];
    unsigned wA = palpha16[(size_t)i * 2 + hw];
    unsigned wB = palpha16[(size_t)(i + 2) * 2 + hw];
    uint2 vA = *(const uint2*)(xr + (size_t)eA * 64);
    uint2 vB = *(const uint2*)(xr + (size_t)eB * 64);
    float pA = f16_at(wA, hsh);
    float pB = f16_at(wB, hsh);
    sA += pA;
    sB += pB;
    a0 = fmaf(pA, bf_lo(vA.x), a0);
    a1 = fmaf(pA, bf_hi(vA.x), a1);
    a2 = fmaf(pA, bf_lo(vA.y), a2);
    a3 = fmaf(pA, bf_hi(vA.y), a3);
    b0 = fmaf(pB, bf_lo(vB.x), b0);
    b1 = fmaf(pB, bf_hi(vB.x), b1);
    b2 = fmaf(pB, bf_lo(vB.y), b2);
    b3 = fmaf(pB, bf_hi(vB.y), b3);
  }
  // remainder: one edge for this half
  if (i < end) {
    int eA = srcs[i];
    unsigned wA = palpha16[(size_t)i * 2 + hw];
    uint2 vA = *(const uint2*)(xr + (size_t)eA * 64);
    float pA = f16_at(wA, hsh);
    sA += pA;
    a0 = fmaf(pA, bf_lo(vA.x), a0);
    a1 = fmaf(pA, bf_hi(vA.x), a1);
    a2 = fmaf(pA, bf_lo(vA.y), a2);
    a3 = fmaf(pA, bf_hi(vA.y), a3);
  }
  float s = sA + sB;
  a0 += b0;
  a1 += b1;
  a2 += b2;
  a3 += b3;
  // combine the two halves (even/odd edge partial sums)
  s += __shfl_xor(s, 32);
  a0 += __shfl_xor(a0, 32);
  a1 += __shfl_xor(a1, 32);
  a2 += __shfl_xor(a2, 32);
  a3 += __shfl_xor(a3, 32);

  if (half == 0) {
    float inv = 1.f / s;
    float4 bv = *(const float4*)&bias[l5 * 4];
    float o0 = fmaf(a0, inv, bv.x);
    float o1 = fmaf(a1, inv, bv.y);
    float o2 = fmaf(a2, inv, bv.z);
    float o3 = fmaf(a3, inv, bv.w);
    o0 = o0 > 0.f ? o0 : fast_exp2(o0 * LOG2E) - 1.f;  // ELU
    o1 = o1 > 0.f ? o1 : fast_exp2(o1 * LOG2E) - 1.f;
    o2 = o2 > 0.f ? o2 : fast_exp2(o2 * LOG2E) - 1.f;
    o3 = o3 > 0.f ? o3 : fast_exp2(o3 * LOG2E) - 1.f;
    f32x4 o = {o0, o1, o2, o3};
    __builtin_nontemporal_store(o, (f32x4*)&out[(size_t)gw * 128 + l5 * 4]);
  }
}

// ---------------------------------------------------------------------------
extern "C" void kernel_launch(void* const* d_in, const int* in_sizes, int n_in,
                              void* d_out, int out_size, void* d_ws, size_t ws_size,
                              hipStream_t stream) {
  const float* x = (const float*)d_in[0];
  const int* ei = (const int*)d_in[1];
  const float* Wm = (const float*)d_in[2];
  const float* att_src = (const float*)d_in[3];
  const float* att_dst = (const float*)d_in[4];
  const float* bias = (const float*)d_in[5];
  float* out = (float*)d_out;

  const int N = in_sizes[0] / 128;
  const int E = in_sizes[1] / 2;
  const int EL = E + N;
  const int NB = (N + 255) >> 8;
  const int NBLK = (EL + CHUNK - 1) / CHUNK;
  const int GB = (N + 127) / 128;

  size_t off = 0;
  auto carve = [&](size_t bytes) -> void* {
    void* p = (char*)d_ws + off;
    off += (bytes + 255) & ~(size_t)255;
    return p;
  };
  unsigned* xwb = (unsigned*)carve((size_t)N * 64 * 4);  // bf16-packed [N][64]
  float* a_src = (float*)carve((size_t)N * 4 * 4);
  float* a_dst = (float*)carve((size_t)N * 4 * 4);
  int* offs = (int*)carve((size_t)(N + 1) * 4);
  int* srcs = (int*)carve((size_t)EL * 4);
  unsigned* tmp = (unsigned*)carve((size_t)EL * 4);
  unsigned* palpha16 = (unsigned*)carve((size_t)EL * 8);  // 4 x f16 per edge
  int* bh = (int*)carve((size_t)NB * NBLK * 4);
  int* btot = (int*)carve((size_t)NB * 4);
  int* bbase = (int*)carve((size_t)NB * 4);

  (void)hipMemsetAsync(btot, 0, (size_t)NB * 4, stream);

  k_fusedA<<<GB + NBLK, 256, 0, stream>>>(x, Wm, att_src, att_dst, xwb, a_src,
                                          a_dst, N, GB, ei, E, EL, NB, NBLK,
                                          bh, btot);
  p2c_brow<<<NB, 256, 0, stream>>>(bh, btot, bbase, NB, NBLK);
  p3_part<<<NBLK, 256, 0, stream>>>(ei, E, EL, NB, NBLK, bh, tmp);
  p4_local<<<NB, 512, 0, stream>>>(tmp, bbase, btot, a_src, a_dst, N, NB, EL,
                                   offs, srcs, palpha16);

  int abl = (int)(((size_t)N * 64 + 255) / 256);
  k_agg<<<abl, 256, 0, stream>>>(srcs, offs, xwb, palpha16, bias, out, N);
}

// Round 12
// 191.239 us; speedup vs baseline: 1.0671x; 1.0639x over previous
//
#include <hip/hip_runtime.h>
#include <cmath>

// ---------------------------------------------------------------------------
// GAT layer: N=100000 nodes, IN=128, OUT=32, H=4 (H*OUT=128), E=1.6M edges.
// Pipeline (5 dispatches):
//   k_hist       : per-block LDS histogram over NB dst-buckets (+btot atomics)
//   p2c_brow     : per-bucket: base = sum(btot[<b]) + scan across blocks
//   k_fusedB     : blocks [0,GB): GEMM xw=x@W bf16-packed + a_src/a_dst logits
//                  blocks [GB,GB+NBLK): p3 partition (independent of GEMM)
//   p4_local     : per-bucket: degree hist + scan -> offs; scatter srcs AND
//                  per-edge softmax numerators palpha16[e] (4 x f16, exp2 form)
//   k_agg        : wave per node, 4 edges in flight per half-wave (8/wave),
//                  4 ch/lane via 8B bf16x4 gather; sum p, p*x; ELU; row write
// ---------------------------------------------------------------------------

#define LOG2E 1.44269504088896340736f

typedef float f32x2 __attribute__((ext_vector_type(2)));
typedef float f32x4 __attribute__((ext_vector_type(4)));
typedef unsigned u32x2 __attribute__((ext_vector_type(2)));

__device__ __forceinline__ float fast_exp2(float x) {
#if __has_builtin(__builtin_amdgcn_exp2f)
  return __builtin_amdgcn_exp2f(x);
#else
  return exp2f(x);
#endif
}

__device__ __forceinline__ unsigned bf16_rne(float f) {
  unsigned u = __float_as_uint(f);
  return (u + 0x7fffu + ((u >> 16) & 1u)) >> 16;
}
__device__ __forceinline__ float bf_lo(unsigned v) {
  return __uint_as_float(v << 16);
}
__device__ __forceinline__ float bf_hi(unsigned v) {
  return __uint_as_float(v & 0xffff0000u);
}
__device__ __forceinline__ float f16_at(unsigned w, int sh) {
  return (float)__builtin_bit_cast(_Float16, (unsigned short)(w >> sh));
}
// pack two f32 -> one u32 of 2 x f16 (RTZ)
__device__ __forceinline__ unsigned pk_f16(float a, float b) {
  auto h = __builtin_amdgcn_cvt_pkrtz(a, b);  // __fp16 ext_vector_type(2)
  return __builtin_bit_cast(unsigned, h);
}

// inclusive block scan; lds must hold >= blockDim/64 ints
__device__ __forceinline__ int blockInclScan(int v, int tid, int* lds) {
  int lane = tid & 63;
  int wid = tid >> 6;
#pragma unroll
  for (int off = 1; off < 64; off <<= 1) {
    int t = __shfl_up(v, off);
    if (lane >= off) v += t;
  }
  if (lane == 63) lds[wid] = v;
  __syncthreads();
  int add = 0;
  for (int i = 0; i < wid; ++i) add += lds[i];
  v += add;
  __syncthreads();
  return v;
}

#define CHUNK 4096

// ---------------- hist: per-block histogram over buckets ----------------
__global__ __launch_bounds__(256) void k_hist(const int* __restrict__ ei, int E,
                                              int EL, int NB, int NBLK,
                                              int* __restrict__ bh,
                                              int* __restrict__ btot) {
  __shared__ int lh[512];
  int tid = threadIdx.x;
  lh[tid] = 0;
  lh[tid + 256] = 0;
  __syncthreads();
  int base_e = blockIdx.x * CHUNK;
#pragma unroll
  for (int j = 0; j < CHUNK / 256; ++j) {
    int e = base_e + j * 256 + tid;
    if (e < EL) {
      int dst = (e < E) ? ei[E + e] : (e - E);
      atomicAdd(&lh[dst >> 8], 1);
    }
  }
  __syncthreads();
  for (int b = tid; b < NB; b += 256) {
    int c = lh[b];
    bh[(size_t)b * NBLK + blockIdx.x] = c;
    if (c) atomicAdd(&btot[b], c);
  }
}

// ---------------- P2c: fused bucket-base + per-bucket row scan ----------------
__global__ __launch_bounds__(256) void p2c_brow(int* __restrict__ bh,
                                                const int* __restrict__ btot,
                                                int* __restrict__ bbase,
                                                int NB, int NBLK) {
  __shared__ int lds[4];
  __shared__ int ctot;
  __shared__ int red[256];
  int b = blockIdx.x;
  int tid = threadIdx.x;
  // base = sum of btot[j] for j < b (folded p2b)
  int part = 0;
  for (int j = tid; j < b; j += 256) part += btot[j];
  red[tid] = part;
  __syncthreads();
  for (int st = 128; st > 0; st >>= 1) {
    if (tid < st) red[tid] += red[tid + st];
    __syncthreads();
  }
  int base = red[0];
  if (tid == 0) bbase[b] = base;
  __syncthreads();
  int v0 = (tid < NBLK) ? bh[(size_t)b * NBLK + tid] : 0;
  int incl0 = blockInclScan(v0, tid, lds);
  if (tid < NBLK) bh[(size_t)b * NBLK + tid] = base + incl0 - v0;
  if (tid == 255) ctot = incl0;
  __syncthreads();
  int base1 = base + ctot;
  int j = 256 + tid;
  int v1 = (j < NBLK) ? bh[(size_t)b * NBLK + j] : 0;
  int incl1 = blockInclScan(v1, tid, lds);
  if (j < NBLK) bh[(size_t)b * NBLK + j] = base1 + incl1 - v1;
}

// ---------------- B: fused GEMM + p3 partition ----------------
// blocks [0,GB): GEMM 128x128 tile; blocks [GB,GB+NBLK): p3 edge partition.
// p3 is independent of GEMM outputs (needs only bh cursors from p2c).
__global__ __launch_bounds__(256) void k_fusedB(
    const float* __restrict__ x, const float* __restrict__ Wm,
    const float* __restrict__ att_src, const float* __restrict__ att_dst,
    unsigned* __restrict__ xwb, float* __restrict__ a_src,
    float* __restrict__ a_dst, int N, int GB,
    const int* __restrict__ ei, int E, int EL, int NB, int NBLK,
    const int* __restrict__ bh, unsigned* __restrict__ tmp) {
  __shared__ __align__(16) char sm[33280];
  const int tid = threadIdx.x;

  if ((int)blockIdx.x >= GB) {
    // ---------------- p3 partition body ----------------
    int blk = blockIdx.x - GB;
    int* lc = (int*)sm;
    for (int b = tid; b < NB; b += 256) lc[b] = bh[(size_t)b * NBLK + blk];
    __syncthreads();
    int base_e = blk * CHUNK;
#pragma unroll
    for (int j = 0; j < CHUNK / 256; ++j) {
      int e = base_e + j * 256 + tid;
      if (e < EL) {
        int src, dst;
        if (e < E) {
          src = ei[e];
          dst = ei[E + e];
        } else {
          src = e - E;
          dst = e - E;
        }
        int pos = atomicAdd(&lc[dst >> 8], 1);
        tmp[pos] = ((unsigned)(dst & 255) << 24) | (unsigned)src;
      }
    }
    return;
  }

  // ---------------- GEMM body ----------------
  float (*xs_t)[132] = (float(*)[132])sm;            // 32*132*4 = 16896 B
  float (*Wl)[128] = (float(*)[128])(sm + 16896);    // 32*128*4 = 16384 B
  const int tx = tid & 15;
  const int ty = tid >> 4;
  const int row0 = blockIdx.x * 128;

  float acc[8][8];
#pragma unroll
  for (int r = 0; r < 8; ++r)
#pragma unroll
    for (int c = 0; c < 8; ++c) acc[r][c] = 0.f;

  for (int kc = 0; kc < 4; ++kc) {
    __syncthreads();
#pragma unroll
    for (int j = 0; j < 4; ++j) {
      int f = tid + j * 256;
      int r = f >> 3, k4 = f & 7;
      int row = row0 + r;
      float4 v = make_float4(0.f, 0.f, 0.f, 0.f);
      if (row < N) v = *(const float4*)&x[(size_t)row * 128 + kc * 32 + k4 * 4];
      xs_t[k4 * 4 + 0][r] = v.x;
      xs_t[k4 * 4 + 1][r] = v.y;
      xs_t[k4 * 4 + 2][r] = v.z;
      xs_t[k4 * 4 + 3][r] = v.w;
    }
#pragma unroll
    for (int j = 0; j < 4; ++j) {
      int f = tid + j * 256;
      int kr = f >> 5, c4 = f & 31;
      *(float4*)&Wl[kr][c4 * 4] =
          *(const float4*)&Wm[(size_t)(kc * 32 + kr) * 128 + c4 * 4];
    }
    __syncthreads();
#pragma unroll 4
    for (int k = 0; k < 32; ++k) {
      float wv[8], xv[8];
      *(float4*)&wv[0] = *(const float4*)&Wl[k][tx * 8];
      *(float4*)&wv[4] = *(const float4*)&Wl[k][tx * 8 + 4];
      *(float4*)&xv[0] = *(const float4*)&xs_t[k][ty * 8];
      *(float4*)&xv[4] = *(const float4*)&xs_t[k][ty * 8 + 4];
#pragma unroll
      for (int r = 0; r < 8; ++r)
#pragma unroll
        for (int c = 0; c < 8; ++c) acc[r][c] = fmaf(xv[r], wv[c], acc[r][c]);
    }
  }

  float att_s[8], att_d[8];
#pragma unroll
  for (int c = 0; c < 8; ++c) {
    att_s[c] = att_src[tx * 8 + c];
    att_d[c] = att_dst[tx * 8 + c];
  }

#pragma unroll
  for (int r = 0; r < 8; ++r) {
    int row = row0 + ty * 8 + r;
    bool ok = row < N;
    float vs = 0.f, vd = 0.f;
#pragma unroll
    for (int c = 0; c < 8; ++c) {
      vs += acc[r][c] * att_s[c];
      vd += acc[r][c] * att_d[c];
    }
    vs += __shfl_xor(vs, 1);
    vs += __shfl_xor(vs, 2);
    vd += __shfl_xor(vd, 1);
    vd += __shfl_xor(vd, 2);
    if (ok) {
      uint4 pk;
      pk.x = bf16_rne(acc[r][0]) | (bf16_rne(acc[r][1]) << 16);
      pk.y = bf16_rne(acc[r][2]) | (bf16_rne(acc[r][3]) << 16);
      pk.z = bf16_rne(acc[r][4]) | (bf16_rne(acc[r][5]) << 16);
      pk.w = bf16_rne(acc[r][6]) | (bf16_rne(acc[r][7]) << 16);
      *(uint4*)&xwb[(size_t)row * 64 + tx * 4] = pk;
      if ((tx & 3) == 0) {
        a_src[row * 4 + (tx >> 2)] = vs * LOG2E;
        a_dst[row * 4 + (tx >> 2)] = vd * LOG2E;
      }
    }
  }
}

// P4: per-bucket local CSR (512 threads): LDS degree hist + scan -> offs;
// scatter srcs AND per-edge softmax numerators palpha16[pos] = 4 x f16
__global__ __launch_bounds__(512) void p4_local(const unsigned* __restrict__ tmp,
                                                const int* __restrict__ bbase,
                                                const int* __restrict__ btot,
                                                const float* __restrict__ asrc,
                                                const float* __restrict__ adst,
                                                int N, int NB, int EL,
                                                int* __restrict__ offs,
                                                int* __restrict__ srcs,
                                                unsigned* __restrict__ palpha16) {
  __shared__ int deg[256];
  __shared__ int cur[256];
  __shared__ f32x4 ads[256];
  __shared__ int lds[8];
  int b = blockIdx.x;
  int tid = threadIdx.x;
  int beg = bbase[b];
  int end = beg + btot[b];
  if (tid < 256) {
    deg[tid] = 0;
    int idx = b * 256 + tid;
    f32x4 z = {0.f, 0.f, 0.f, 0.f};
    ads[tid] = (idx < N) ? *(const f32x4*)&adst[idx * 4] : z;
  }
  __syncthreads();
  for (int k = beg + tid; k < end; k += 512) {
    unsigned w = tmp[k];
    atomicAdd(&deg[w >> 24], 1);
  }
  __syncthreads();
  int v = (tid < 256) ? deg[tid] : 0;
  int incl = blockInclScan(v, tid, lds);
  if (tid < 256) {
    int excl = incl - v;
    int idx = b * 256 + tid;
    if (idx < N) offs[idx] = beg + excl;
    cur[tid] = beg + excl;
  }
  if (b == NB - 1 && tid == 0) offs[N] = EL;
  __syncthreads();
  for (int k = beg + tid; k < end; k += 512) {
    unsigned w = tmp[k];
    int dloc = w >> 24;
    int src = (int)(w & 0xFFFFFFu);
    int pos = atomicAdd(&cur[dloc], 1);
    srcs[pos] = src;
    f32x4 as = *(const f32x4*)&asrc[src * 4];
    f32x4 ad = ads[dloc];
    float t0 = as.x + ad.x, t1 = as.y + ad.y, t2 = as.z + ad.z, t3 = as.w + ad.w;
    float p0 = fast_exp2(fmaxf(t0, 0.2f * t0));
    float p1 = fast_exp2(fmaxf(t1, 0.2f * t1));
    float p2 = fast_exp2(fmaxf(t2, 0.2f * t2));
    float p3 = fast_exp2(fmaxf(t3, 0.2f * t3));
    u32x2 st;
    st.x = pk_f16(p0, p1);
    st.y = pk_f16(p2, p3);
    *(u32x2*)&palpha16[(size_t)pos * 2] = st;
  }
}

// ---------------- K3: per-node aggregate (R10 body) ----------------
// wave per node; half-wave 0 = even edges, half-wave 1 = odd edges.
// lane covers 4 channels (uint2 = 4 bf16).  4 edges in flight per half-wave.
__global__ __launch_bounds__(256) void k_agg(
    const int* __restrict__ srcs, const int* __restrict__ offs,
    const unsigned* __restrict__ xwb, const unsigned* __restrict__ palpha16,
    const float* __restrict__ bias, float* __restrict__ out, int N) {
  int gw = (int)(((size_t)blockIdx.x * blockDim.x + threadIdx.x) >> 6);
  int lane = threadIdx.x & 63;
  if (gw >= N) return;
  int beg = offs[gw];
  int end = offs[gw + 1];
  int half = lane >> 5;
  int l5 = lane & 31;
  int h = l5 >> 3;           // head of this lane's 4 channels
  int hw = h >> 1;           // which palpha16 word
  int hsh = (h & 1) * 16;    // shift within word
  const unsigned* xr = xwb + l5 * 2;

  float sA = 0.f, sB = 0.f;
  float a0 = 0.f, a1 = 0.f, a2 = 0.f, a3 = 0.f;
  float b0 = 0.f, b1 = 0.f, b2 = 0.f, b3 = 0.f;
  int i = beg + half;
  // main: 4 edges per half-wave in flight (8 per wave)
  for (; i + 6 < end; i += 8) {
    int eA = srcs[i], eB = srcs[i + 2], eC = srcs[i + 4], eD = srcs[i + 6];
    unsigned wA = palpha16[(size_t)i * 2 + hw];
    unsigned wB = palpha16[(size_t)(i + 2) * 2 + hw];
    unsigned wC = palpha16[(size_t)(i + 4) * 2 + hw];
    unsigned wD = palpha16[(size_t)(i + 6) * 2 + hw];
    uint2 vA = *(const uint2*)(xr + (size_t)eA * 64);
    uint2 vB = *(const uint2*)(xr + (size_t)eB * 64);
    uint2 vC = *(const uint2*)(xr + (size_t)eC * 64);
    uint2 vD = *(const uint2*)(xr + (size_t)eD * 64);
    float pA = f16_at(wA, hsh);
    float pB = f16_at(wB, hsh);
    float pC = f16_at(wC, hsh);
    float pD = f16_at(wD, hsh);
    sA += pA + pC;
    sB += pB + pD;
    a0 = fmaf(pA, bf_lo(vA.x), a0);
    a1 = fmaf(pA, bf_hi(vA.x), a1);
    a2 = fmaf(pA, bf_lo(vA.y), a2);
    a3 = fmaf(pA, bf_hi(vA.y), a3);
    b0 = fmaf(pB, bf_lo(vB.x), b0);
    b1 = fmaf(pB, bf_hi(vB.x), b1);
    b2 = fmaf(pB, bf_lo(vB.y), b2);
    b3 = fmaf(pB, bf_hi(vB.y), b3);
    a0 = fmaf(pC, bf_lo(vC.x), a0);
    a1 = fmaf(pC, bf_hi(vC.x), a1);
    a2 = fmaf(pC, bf_lo(vC.y), a2);
    a3 = fmaf(pC, bf_hi(vC.y), a3);
    b0 = fmaf(pD, bf_lo(vD.x), b0);
    b1 = fmaf(pD, bf_hi(vD.x), b1);
    b2 = fmaf(pD, bf_lo(vD.y), b2);
    b3 = fmaf(pD, bf_hi(vD.y), b3);
  }
  // remainder: one edge at a time for this half
  for (; i < end; i += 2) {
    int eA = srcs[i];
    unsigned wA = palpha16[(size_t)i * 2 + hw];
    uint2 vA = *(const uint2*)(xr + (size_t)eA * 64);
    float pA = f16_at(wA, hsh);
    sA += pA;
    a0 = fmaf(pA, bf_lo(vA.x), a0);
    a1 = fmaf(pA, bf_hi(vA.x), a1);
    a2 = fmaf(pA, bf_lo(vA.y), a2);
    a3 = fmaf(pA, bf_hi(vA.y), a3);
  }
  float s = sA + sB;
  a0 += b0;
  a1 += b1;
  a2 += b2;
  a3 += b3;
  // combine the two halves (even/odd edge partial sums)
  s += __shfl_xor(s, 32);
  a0 += __shfl_xor(a0, 32);
  a1 += __shfl_xor(a1, 32);
  a2 += __shfl_xor(a2, 32);
  a3 += __shfl_xor(a3, 32);

  if (half == 0) {
    float inv = 1.f / s;
    float4 bv = *(const float4*)&bias[l5 * 4];
    float o0 = fmaf(a0, inv, bv.x);
    float o1 = fmaf(a1, inv, bv.y);
    float o2 = fmaf(a2, inv, bv.z);
    float o3 = fmaf(a3, inv, bv.w);
    o0 = o0 > 0.f ? o0 : fast_exp2(o0 * LOG2E) - 1.f;  // ELU
    o1 = o1 > 0.f ? o1 : fast_exp2(o1 * LOG2E) - 1.f;
    o2 = o2 > 0.f ? o2 : fast_exp2(o2 * LOG2E) - 1.f;
    o3 = o3 > 0.f ? o3 : fast_exp2(o3 * LOG2E) - 1.f;
    f32x4 o = {o0, o1, o2, o3};
    __builtin_nontemporal_store(o, (f32x4*)&out[(size_t)gw * 128 + l5 * 4]);
  }
}

// ---------------------------------------------------------------------------
extern "C" void kernel_launch(void* const* d_in, const int* in_sizes, int n_in,
                              void* d_out, int out_size, void* d_ws, size_t ws_size,
                              hipStream_t stream) {
  const float* x = (const float*)d_in[0];
  const int* ei = (const int*)d_in[1];
  const float* Wm = (const float*)d_in[2];
  const float* att_src = (const float*)d_in[3];
  const float* att_dst = (const float*)d_in[4];
  const float* bias = (const float*)d_in[5];
  float* out = (float*)d_out;

  const int N = in_sizes[0] / 128;
  const int E = in_sizes[1] / 2;
  const int EL = E + N;
  const int NB = (N + 255) >> 8;
  const int NBLK = (EL + CHUNK - 1) / CHUNK;
  const int GB = (N + 127) / 128;

  size_t off = 0;
  auto carve = [&](size_t bytes) -> void* {
    void* p = (char*)d_ws + off;
    off += (bytes + 255) & ~(size_t)255;
    return p;
  };
  unsigned* xwb = (unsigned*)carve((size_t)N * 64 * 4);  // bf16-packed [N][64]
  float* a_src = (float*)carve((size_t)N * 4 * 4);
  float* a_dst = (float*)carve((size_t)N * 4 * 4);
  int* offs = (int*)carve((size_t)(N + 1) * 4);
  int* srcs = (int*)carve((size_t)EL * 4);
  unsigned* tmp = (unsigned*)carve((size_t)EL * 4);
  unsigned* palpha16 = (unsigned*)carve((size_t)EL * 8);  // 4 x f16 per edge
  int* bh = (int*)carve((size_t)NB * NBLK * 4);
  int* btot = (int*)carve((size_t)NB * 4);
  int* bbase = (int*)carve((size_t)NB * 4);

  (void)hipMemsetAsync(btot, 0, (size_t)NB * 4, stream);

  k_hist<<<NBLK, 256, 0, stream>>>(ei, E, EL, NB, NBLK, bh, btot);
  p2c_brow<<<NB, 256, 0, stream>>>(bh, btot, bbase, NB, NBLK);
  k_fusedB<<<GB + NBLK, 256, 0, stream>>>(x, Wm, att_src, att_dst, xwb, a_src,
                                          a_dst, N, GB, ei, E, EL, NB, NBLK,
                                          bh, tmp);
  p4_local<<<NB, 512, 0, stream>>>(tmp, bbase, btot, a_src, a_dst, N, NB, EL,
                                   offs, srcs, palpha16);

  int abl = (int)(((size_t)N * 64 + 255) / 256);
  k_agg<<<abl, 256, 0, stream>>>(srcs, offs, xwb, palpha16, bias, out, N);
}

// Round 13
// 174.067 us; speedup vs baseline: 1.1724x; 1.0987x over previous
//
#include <hip/hip_runtime.h>
#include <cmath>

// ---------------------------------------------------------------------------
// GAT layer: N=100000 nodes, IN=128, OUT=32, H=4 (H*OUT=128), E=1.6M edges.
// Pipeline (4 dispatches + memset):
//   k_hist       : per-block LDS histogram over NB dst-buckets (+btot atomics)
//   p2c_brow     : per-bucket: base = sum(btot[<b]) + scan across blocks
//   k_fusedB     : blocks [0,GB): GEMM xw=x@W bf16-packed + a_src/a_dst logits
//                  blocks [GB,GB+NBLK): p3 partition (independent of GEMM)
//   k_bagg       : per (bucket, quarter): counting-sort the bucket's tmp
//                  segment into LDS, then wave-per-dst aggregation with
//                  inline f32 softmax numerators; bias+ELU; direct out write.
//                  (fuses old p4_local + k_agg; no srcs/palpha/offs arrays)
// ---------------------------------------------------------------------------

#define LOG2E 1.44269504088896340736f

typedef float f32x2 __attribute__((ext_vector_type(2)));
typedef float f32x4 __attribute__((ext_vector_type(4)));

__device__ __forceinline__ float fast_exp2(float x) {
#if __has_builtin(__builtin_amdgcn_exp2f)
  return __builtin_amdgcn_exp2f(x);
#else
  return exp2f(x);
#endif
}

__device__ __forceinline__ unsigned bf16_rne(float f) {
  unsigned u = __float_as_uint(f);
  return (u + 0x7fffu + ((u >> 16) & 1u)) >> 16;
}
__device__ __forceinline__ float bf_lo(unsigned v) {
  return __uint_as_float(v << 16);
}
__device__ __forceinline__ float bf_hi(unsigned v) {
  return __uint_as_float(v & 0xffff0000u);
}

// inclusive block scan; lds must hold >= blockDim/64 ints
__device__ __forceinline__ int blockInclScan(int v, int tid, int* lds) {
  int lane = tid & 63;
  int wid = tid >> 6;
#pragma unroll
  for (int off = 1; off < 64; off <<= 1) {
    int t = __shfl_up(v, off);
    if (lane >= off) v += t;
  }
  if (lane == 63) lds[wid] = v;
  __syncthreads();
  int add = 0;
  for (int i = 0; i < wid; ++i) add += lds[i];
  v += add;
  __syncthreads();
  return v;
}

#define CHUNK 4096
#define MAXE 3072  // max edges per (bucket, quarter); avg ~1150, 4.5-sigma ~1300

// ---------------- hist: per-block histogram over buckets ----------------
__global__ __launch_bounds__(256) void k_hist(const int* __restrict__ ei, int E,
                                              int EL, int NB, int NBLK,
                                              int* __restrict__ bh,
                                              int* __restrict__ btot) {
  __shared__ int lh[512];
  int tid = threadIdx.x;
  lh[tid] = 0;
  lh[tid + 256] = 0;
  __syncthreads();
  int base_e = blockIdx.x * CHUNK;
#pragma unroll
  for (int j = 0; j < CHUNK / 256; ++j) {
    int e = base_e + j * 256 + tid;
    if (e < EL) {
      int dst = (e < E) ? ei[E + e] : (e - E);
      atomicAdd(&lh[dst >> 8], 1);
    }
  }
  __syncthreads();
  for (int b = tid; b < NB; b += 256) {
    int c = lh[b];
    bh[(size_t)b * NBLK + blockIdx.x] = c;
    if (c) atomicAdd(&btot[b], c);
  }
}

// ---------------- P2c: fused bucket-base + per-bucket row scan ----------------
__global__ __launch_bounds__(256) void p2c_brow(int* __restrict__ bh,
                                                const int* __restrict__ btot,
                                                int* __restrict__ bbase,
                                                int NB, int NBLK) {
  __shared__ int lds[4];
  __shared__ int ctot;
  __shared__ int red[256];
  int b = blockIdx.x;
  int tid = threadIdx.x;
  // base = sum of btot[j] for j < b
  int part = 0;
  for (int j = tid; j < b; j += 256) part += btot[j];
  red[tid] = part;
  __syncthreads();
  for (int st = 128; st > 0; st >>= 1) {
    if (tid < st) red[tid] += red[tid + st];
    __syncthreads();
  }
  int base = red[0];
  if (tid == 0) bbase[b] = base;
  __syncthreads();
  int v0 = (tid < NBLK) ? bh[(size_t)b * NBLK + tid] : 0;
  int incl0 = blockInclScan(v0, tid, lds);
  if (tid < NBLK) bh[(size_t)b * NBLK + tid] = base + incl0 - v0;
  if (tid == 255) ctot = incl0;
  __syncthreads();
  int base1 = base + ctot;
  int j = 256 + tid;
  int v1 = (j < NBLK) ? bh[(size_t)b * NBLK + j] : 0;
  int incl1 = blockInclScan(v1, tid, lds);
  if (j < NBLK) bh[(size_t)b * NBLK + j] = base1 + incl1 - v1;
}

// ---------------- B: fused GEMM + p3 partition ----------------
// blocks [0,GB): GEMM 128x128 tile; blocks [GB,GB+NBLK): p3 edge partition.
__global__ __launch_bounds__(256) void k_fusedB(
    const float* __restrict__ x, const float* __restrict__ Wm,
    const float* __restrict__ att_src, const float* __restrict__ att_dst,
    unsigned* __restrict__ xwb, float* __restrict__ a_src,
    float* __restrict__ a_dst, int N, int GB,
    const int* __restrict__ ei, int E, int EL, int NB, int NBLK,
    const int* __restrict__ bh, unsigned* __restrict__ tmp) {
  __shared__ __align__(16) char sm[33280];
  const int tid = threadIdx.x;

  if ((int)blockIdx.x >= GB) {
    // ---------------- p3 partition body ----------------
    int blk = blockIdx.x - GB;
    int* lc = (int*)sm;
    for (int b = tid; b < NB; b += 256) lc[b] = bh[(size_t)b * NBLK + blk];
    __syncthreads();
    int base_e = blk * CHUNK;
#pragma unroll
    for (int j = 0; j < CHUNK / 256; ++j) {
      int e = base_e + j * 256 + tid;
      if (e < EL) {
        int src, dst;
        if (e < E) {
          src = ei[e];
          dst = ei[E + e];
        } else {
          src = e - E;
          dst = e - E;
        }
        int pos = atomicAdd(&lc[dst >> 8], 1);
        tmp[pos] = ((unsigned)(dst & 255) << 24) | (unsigned)src;
      }
    }
    return;
  }

  // ---------------- GEMM body ----------------
  float (*xs_t)[132] = (float(*)[132])sm;            // 32*132*4 = 16896 B
  float (*Wl)[128] = (float(*)[128])(sm + 16896);    // 32*128*4 = 16384 B
  const int tx = tid & 15;
  const int ty = tid >> 4;
  const int row0 = blockIdx.x * 128;

  float acc[8][8];
#pragma unroll
  for (int r = 0; r < 8; ++r)
#pragma unroll
    for (int c = 0; c < 8; ++c) acc[r][c] = 0.f;

  for (int kc = 0; kc < 4; ++kc) {
    __syncthreads();
#pragma unroll
    for (int j = 0; j < 4; ++j) {
      int f = tid + j * 256;
      int r = f >> 3, k4 = f & 7;
      int row = row0 + r;
      float4 v = make_float4(0.f, 0.f, 0.f, 0.f);
      if (row < N) v = *(const float4*)&x[(size_t)row * 128 + kc * 32 + k4 * 4];
      xs_t[k4 * 4 + 0][r] = v.x;
      xs_t[k4 * 4 + 1][r] = v.y;
      xs_t[k4 * 4 + 2][r] = v.z;
      xs_t[k4 * 4 + 3][r] = v.w;
    }
#pragma unroll
    for (int j = 0; j < 4; ++j) {
      int f = tid + j * 256;
      int kr = f >> 5, c4 = f & 31;
      *(float4*)&Wl[kr][c4 * 4] =
          *(const float4*)&Wm[(size_t)(kc * 32 + kr) * 128 + c4 * 4];
    }
    __syncthreads();
#pragma unroll 4
    for (int k = 0; k < 32; ++k) {
      float wv[8], xv[8];
      *(float4*)&wv[0] = *(const float4*)&Wl[k][tx * 8];
      *(float4*)&wv[4] = *(const float4*)&Wl[k][tx * 8 + 4];
      *(float4*)&xv[0] = *(const float4*)&xs_t[k][ty * 8];
      *(float4*)&xv[4] = *(const float4*)&xs_t[k][ty * 8 + 4];
#pragma unroll
      for (int r = 0; r < 8; ++r)
#pragma unroll
        for (int c = 0; c < 8; ++c) acc[r][c] = fmaf(xv[r], wv[c], acc[r][c]);
    }
  }

  float att_s[8], att_d[8];
#pragma unroll
  for (int c = 0; c < 8; ++c) {
    att_s[c] = att_src[tx * 8 + c];
    att_d[c] = att_dst[tx * 8 + c];
  }

#pragma unroll
  for (int r = 0; r < 8; ++r) {
    int row = row0 + ty * 8 + r;
    bool ok = row < N;
    float vs = 0.f, vd = 0.f;
#pragma unroll
    for (int c = 0; c < 8; ++c) {
      vs += acc[r][c] * att_s[c];
      vd += acc[r][c] * att_d[c];
    }
    vs += __shfl_xor(vs, 1);
    vs += __shfl_xor(vs, 2);
    vd += __shfl_xor(vd, 1);
    vd += __shfl_xor(vd, 2);
    if (ok) {
      uint4 pk;
      pk.x = bf16_rne(acc[r][0]) | (bf16_rne(acc[r][1]) << 16);
      pk.y = bf16_rne(acc[r][2]) | (bf16_rne(acc[r][3]) << 16);
      pk.z = bf16_rne(acc[r][4]) | (bf16_rne(acc[r][5]) << 16);
      pk.w = bf16_rne(acc[r][6]) | (bf16_rne(acc[r][7]) << 16);
      *(uint4*)&xwb[(size_t)row * 64 + tx * 4] = pk;
      if ((tx & 3) == 0) {
        a_src[row * 4 + (tx >> 2)] = vs * LOG2E;
        a_dst[row * 4 + (tx >> 2)] = vd * LOG2E;
      }
    }
  }
}

// ---------------- k_bagg: fused per-bucket sort + aggregate ----------------
// grid NB*4; block (b = bid>>2, quarter p = bid&3) owns dst [b*256+p*64, +64).
// Pass 1: scan bucket's tmp segment, count degrees of our 64 dst (LDS).
// Pass 2: counting-sort our edges into LDS `sorted`.
// Pass 3: wave wv aggregates dst p*64 + wv+4j (16 dst/wave): inline f32
// softmax numerator (exp2-form logits), bf16x4 xw gather, bias+ELU, NT write.
__global__ __launch_bounds__(256) void k_bagg(
    const unsigned* __restrict__ tmp, const int* __restrict__ bbase,
    const int* __restrict__ btot, const float* __restrict__ asrc,
    const float* __restrict__ adst, const unsigned* __restrict__ xwb,
    const float* __restrict__ bias, float* __restrict__ out, int N) {
  __shared__ unsigned sorted[MAXE];
  __shared__ int deg[64];
  __shared__ int startd[64];
  __shared__ int cur[64];
  const int bid = blockIdx.x;
  const int b = bid >> 2;
  const int p = bid & 3;
  const int tid = threadIdx.x;
  const int beg = bbase[b];
  const int cnt = btot[b];
  if (tid < 64) deg[tid] = 0;
  __syncthreads();
  // pass 1: degree count for our quarter
  for (int k = tid; k < cnt; k += 256) {
    unsigned w = tmp[beg + k];
    int dloc = w >> 24;
    if ((dloc >> 6) == p) atomicAdd(&deg[dloc & 63], 1);
  }
  __syncthreads();
  // scan deg -> startd/cur (first wave)
  if (tid < 64) {
    int v = deg[tid];
    int incl = v;
#pragma unroll
    for (int off = 1; off < 64; off <<= 1) {
      int t = __shfl_up(incl, off);
      if (tid >= off) incl += t;
    }
    int excl = incl - v;
    startd[tid] = excl;
    cur[tid] = excl;
  }
  __syncthreads();
  // pass 2: counting-sort our edges into LDS (cap at MAXE for safety)
  for (int k = tid; k < cnt; k += 256) {
    unsigned w = tmp[beg + k];
    int dloc = w >> 24;
    if ((dloc >> 6) == p) {
      int pos = atomicAdd(&cur[dloc & 63], 1);
      if (pos < MAXE) sorted[pos] = w;
    }
  }
  __syncthreads();
  // pass 3: aggregation
  const int wv = tid >> 6;
  const int lane = tid & 63;
  const int half = lane >> 5;
  const int l5 = lane & 31;
  const int h = l5 >> 3;  // head of this lane's 4 channels
  const unsigned* xr = xwb + l5 * 2;
  const float4 bv = *(const float4*)&bias[l5 * 4];

  for (int j = 0; j < 16; ++j) {
    int dl = wv + 4 * j;
    int gdst = b * 256 + p * 64 + dl;
    if (gdst >= N) break;  // wave-uniform (dl uniform across wave)
    int sd = startd[dl];
    int ed = min(sd + deg[dl], MAXE);
    float ad = adst[gdst * 4 + h];

    float sA = 0.f, sB = 0.f;
    float a0 = 0.f, a1 = 0.f, a2 = 0.f, a3 = 0.f;
    float b0 = 0.f, b1 = 0.f, b2 = 0.f, b3 = 0.f;
    int i = sd + half;
    // 4 edges per half-wave in flight (8 per wave)
    for (; i + 6 < ed; i += 8) {
      unsigned wA = sorted[i], wB = sorted[i + 2];
      unsigned wC = sorted[i + 4], wD = sorted[i + 6];
      int eA = wA & 0xFFFFFF, eB = wB & 0xFFFFFF;
      int eC = wC & 0xFFFFFF, eD = wD & 0xFFFFFF;
      float tA = asrc[eA * 4 + h] + ad;
      float tB = asrc[eB * 4 + h] + ad;
      float tC = asrc[eC * 4 + h] + ad;
      float tD = asrc[eD * 4 + h] + ad;
      uint2 vA = *(const uint2*)(xr + (size_t)eA * 64);
      uint2 vB = *(const uint2*)(xr + (size_t)eB * 64);
      uint2 vC = *(const uint2*)(xr + (size_t)eC * 64);
      uint2 vD = *(const uint2*)(xr + (size_t)eD * 64);
      float pA = fast_exp2(fmaxf(tA, 0.2f * tA));
      float pB = fast_exp2(fmaxf(tB, 0.2f * tB));
      float pC = fast_exp2(fmaxf(tC, 0.2f * tC));
      float pD = fast_exp2(fmaxf(tD, 0.2f * tD));
      sA += pA + pC;
      sB += pB + pD;
      a0 = fmaf(pA, bf_lo(vA.x), a0);
      a1 = fmaf(pA, bf_hi(vA.x), a1);
      a2 = fmaf(pA, bf_lo(vA.y), a2);
      a3 = fmaf(pA, bf_hi(vA.y), a3);
      b0 = fmaf(pB, bf_lo(vB.x), b0);
      b1 = fmaf(pB, bf_hi(vB.x), b1);
      b2 = fmaf(pB, bf_lo(vB.y), b2);
      b3 = fmaf(pB, bf_hi(vB.y), b3);
      a0 = fmaf(pC, bf_lo(vC.x), a0);
      a1 = fmaf(pC, bf_hi(vC.x), a1);
      a2 = fmaf(pC, bf_lo(vC.y), a2);
      a3 = fmaf(pC, bf_hi(vC.y), a3);
      b0 = fmaf(pD, bf_lo(vD.x), b0);
      b1 = fmaf(pD, bf_hi(vD.x), b1);
      b2 = fmaf(pD, bf_lo(vD.y), b2);
      b3 = fmaf(pD, bf_hi(vD.y), b3);
    }
    for (; i < ed; i += 2) {
      unsigned wA = sorted[i];
      int eA = wA & 0xFFFFFF;
      float tA = asrc[eA * 4 + h] + ad;
      uint2 vA = *(const uint2*)(xr + (size_t)eA * 64);
      float pA = fast_exp2(fmaxf(tA, 0.2f * tA));
      sA += pA;
      a0 = fmaf(pA, bf_lo(vA.x), a0);
      a1 = fmaf(pA, bf_hi(vA.x), a1);
      a2 = fmaf(pA, bf_lo(vA.y), a2);
      a3 = fmaf(pA, bf_hi(vA.y), a3);
    }
    float s = sA + sB;
    a0 += b0;
    a1 += b1;
    a2 += b2;
    a3 += b3;
    s += __shfl_xor(s, 32);
    a0 += __shfl_xor(a0, 32);
    a1 += __shfl_xor(a1, 32);
    a2 += __shfl_xor(a2, 32);
    a3 += __shfl_xor(a3, 32);

    if (half == 0) {
      float inv = 1.f / s;
      float o0 = fmaf(a0, inv, bv.x);
      float o1 = fmaf(a1, inv, bv.y);
      float o2 = fmaf(a2, inv, bv.z);
      float o3 = fmaf(a3, inv, bv.w);
      o0 = o0 > 0.f ? o0 : fast_exp2(o0 * LOG2E) - 1.f;  // ELU
      o1 = o1 > 0.f ? o1 : fast_exp2(o1 * LOG2E) - 1.f;
      o2 = o2 > 0.f ? o2 : fast_exp2(o2 * LOG2E) - 1.f;
      o3 = o3 > 0.f ? o3 : fast_exp2(o3 * LOG2E) - 1.f;
      f32x4 o = {o0, o1, o2, o3};
      __builtin_nontemporal_store(o, (f32x4*)&out[(size_t)gdst * 128 + l5 * 4]);
    }
  }
}

// ---------------------------------------------------------------------------
extern "C" void kernel_launch(void* const* d_in, const int* in_sizes, int n_in,
                              void* d_out, int out_size, void* d_ws, size_t ws_size,
                              hipStream_t stream) {
  const float* x = (const float*)d_in[0];
  const int* ei = (const int*)d_in[1];
  const float* Wm = (const float*)d_in[2];
  const float* att_src = (const float*)d_in[3];
  const float* att_dst = (const float*)d_in[4];
  const float* bias = (const float*)d_in[5];
  float* out = (float*)d_out;

  const int N = in_sizes[0] / 128;
  const int E = in_sizes[1] / 2;
  const int EL = E + N;
  const int NB = (N + 255) >> 8;
  const int NBLK = (EL + CHUNK - 1) / CHUNK;
  const int GB = (N + 127) / 128;

  size_t off = 0;
  auto carve = [&](size_t bytes) -> void* {
    void* p = (char*)d_ws + off;
    off += (bytes + 255) & ~(size_t)255;
    return p;
  };
  unsigned* xwb = (unsigned*)carve((size_t)N * 64 * 4);  // bf16-packed [N][64]
  float* a_src = (float*)carve((size_t)N * 4 * 4);
  float* a_dst = (float*)carve((size_t)N * 4 * 4);
  unsigned* tmp = (unsigned*)carve((size_t)EL * 4);
  int* bh = (int*)carve((size_t)NB * NBLK * 4);
  int* btot = (int*)carve((size_t)NB * 4);
  int* bbase = (int*)carve((size_t)NB * 4);

  (void)hipMemsetAsync(btot, 0, (size_t)NB * 4, stream);

  k_hist<<<NBLK, 256, 0, stream>>>(ei, E, EL, NB, NBLK, bh, btot);
  p2c_brow<<<NB, 256, 0, stream>>>(bh, btot, bbase, NB, NBLK);
  k_fusedB<<<GB + NBLK, 256, 0, stream>>>(x, Wm, att_src, att_dst, xwb, a_src,
                                          a_dst, N, GB, ei, E, EL, NB, NBLK,
                                          bh, tmp);
  k_bagg<<<NB * 4, 256, 0, stream>>>(tmp, bbase, btot, a_src, a_dst, xwb,
                                     bias, out, N);
}